// Round 8
// baseline (284.309 us; speedup 1.0000x reference)
//
#include <hip/hip_runtime.h>
#include <math.h>

#define NN 1024
#define BATCH 32
#define NPAIR 16          // batch pairs: block handles batches (q, q+16)
#define P 8               // stage blocks per pair
#define NW 4              // waves per block
#define THREADS 256
#define DD 32             // diagonals per interval (needs 65-DD >= SW)
#define SW 32             // row stride between waves
#define SPAN 160          // (NW-1)*SW + 64
#define NT 64             // ceil(2047/DD)
#define RB 4              // ring slots per interface
#define GW 0.05f
#define K2 144.2695040888963f            // (1/gamma)*log2(e): scaled domain
#define INV_K2 0.0069314718055994531f    // gamma*ln2
#define BIGS 1.4426950408889634e11f      // 1e9 * K2

#define EXP2F(x) __builtin_amdgcn_exp2f(x)
#define LOG2F(x) __builtin_amdgcn_logf(x)   // v_log_f32 = log2

union F2U { float2 f; unsigned long long u; };

// lanes 1..63 <- src[lane-1]; lane 0 <- oldv[0] (DPP wave_shr:1, bound_ctrl=false)
__device__ __forceinline__ float dppshr(float oldv, float src) {
    return __int_as_float(__builtin_amdgcn_update_dpp(
        __float_as_int(oldv), __float_as_int(src), 0x138, 0xF, 0xF, false));
}

// Overlapped-band wavefront soft-DTW. TWO independent batches per block
// (ILP=2 fills chain/DPP/exchange stalls -- r5 vs r7 proved we are
// latency-bound, not issue-bound). Geometry/protocol identical to passing r7.
// d-loop carries R as (m,s), R = m - log2(s); collapse to scalar per interval.
// Flags/acks: 0xAA poison reads negative = "not ready" (no init kernel).
__global__ __launch_bounds__(THREADS) void sdtw_pair(
        const float* __restrict__ inp, const float* __restrict__ tgt,
        float* __restrict__ out, int* __restrict__ flags,
        int* __restrict__ acks, unsigned long long* __restrict__ gx)
{
    __shared__ float xsA[NN], xsB[NN];
    __shared__ float wlblk[3136];    // [guard 544 | O:1024 | E:1024 | guard 544]
    __shared__ float4 exch[2][SPAN];

    const int bid = blockIdx.x;      // 128 blocks
    const int q = bid & 15;          // pair id; stages of a pair share XCD (bid%8=q%8)
    const int p = bid >> 4;          // stage
    const int bA = q, bB = q + NPAIR;
    const int tid = threadIdx.x;
    const int w = tid >> 6;
    const int lane = tid & 63;

    for (int tdx = tid; tdx < NN; tdx += THREADS) {
        xsA[tdx] = inp[bA * NN + tdx];
        xsB[tdx] = inp[bB * NN + tdx];
        float mO = (float)(2 * tdx + 1) - 1023.0f;
        float mE = (float)(2 * tdx) - 1023.0f;
        wlblk[544 + tdx]        = K2 / (1.0f + __expf(-GW * (fabsf(mO) - 512.0f)));
        wlblk[544 + 1024 + tdx] = K2 / (1.0f + __expf(-GW * (fabsf(mE) - 512.0f)));
    }

    const int i = 128 * p - (DD - 1) + SW * w + lane;   // owned row (may be OOB)
    const int i0 = i - lane;                            // wave's base row
    const bool rowValid = (unsigned)i < (unsigned)NN;
    int ic = min(max(i, 0), NN - 1);
    const float tiA = tgt[bA * NN + ic];
    const float tiB = tgt[bB * NN + ic];
    const int imask = rowValid ? i : 0x3FFFFFFF;        // forces jj0 very negative
    const float* wpBase = &wlblk[544 + 511 - i];        // parity-split LUT base

    // pair state per batch: R(i,k-1) = m1 - log2(s1); R(i,k-2) = m2 - log2(s2)
    float m1A = BIGS, s1A = 1.0f, m2A = BIGS, s2A = 1.0f;
    float m1B = BIGS, s1B = 1.0f, m2B = BIGS, s2B = 1.0f;
    float mdgpA = (i == 0) ? 0.0f : BIGS, sdgpA = 1.0f;
    float mdgpB = mdgpA, sdgpB = 1.0f;
    float bndUpMA = BIGS, bndUpMB = BIGS;   // lane-0 'up' feeds (s-feed is always 1)
    float xvA = 0.0f, xvB = 0.0f;
    int ackC = 0;

    __syncthreads();

    const int fin = q * P + p;              // inbound interface (p>0)
    const int fout = fin + 1;               // outbound interface (p<P-1)
    unsigned long long* gout = gx + (size_t)fout * RB * DD * 2;
    const unsigned long long* ginb = gx + (size_t)fin * RB * DD * 2;

    for (int t = 0; t < NT; ++t) {
        if (w == NW - 1 && p < P - 1 && t >= RB && ackC <= t - RB) {
            ackC = __hip_atomic_load(&acks[fout], __ATOMIC_RELAXED,
                                     __HIP_MEMORY_SCOPE_AGENT);
        }

        const int kbase = t << 5;
        const float* wp = wpBase + (t << 4);            // parity LUT, +16/interval
        int c = kbase - 1 - i;  c = min(max(c, 0), NN - 1);
        xvA = xsA[c]; xvB = xsB[c];                     // re-init x rotations
        int c0 = kbase - i0;    c0 = min(max(c0, 0), NN - 1);
        const float xf0A = xsA[c0], xf0B = xsB[c0];     // uniform d=0 lane-0 feeds
        const int jj0 = kbase - imask;                  // j at d=0 (or very negative)

        #pragma unroll
        for (int d = 0; d < DD; ++d) {
            const float wv = (d & 1) ? wp[1024 + ((d + 1) >> 1)] : wp[(d >> 1)];
            const bool vmask = (jj0 >= -d);
            // ---- batch A ----
            xvA = dppshr((d == 0) ? xf0A : xvA, xvA);
            {
                const float mUp = dppshr((d == 0) ? bndUpMA : m1A, m1A);
                const float sUp = dppshr((d == 0) ? 1.0f : s1A, s1A);
                const float mDg = mdgpA, sDg = sdgpA;
                const float mLf = m1A,  sLf = s1A;
                const float diff = tiA - xvA;
                const float dk = diff * diff * wv;
                const float M = fminf(fminf(mDg, mUp), mLf);
                const float eDg = EXP2F(M - mDg);
                const float eUp = EXP2F(M - mUp);
                const float eLf = EXP2F(M - mLf);
                const float sN = sDg * eDg + sUp * eUp + sLf * eLf;
                float mN = dk + M;
                mN = vmask ? mN : BIGS;
                m2A = m1A; s2A = s1A; m1A = mN; s1A = sN;
                mdgpA = mUp; sdgpA = sUp;
            }
            // ---- batch B ----
            xvB = dppshr((d == 0) ? xf0B : xvB, xvB);
            {
                const float mUp = dppshr((d == 0) ? bndUpMB : m1B, m1B);
                const float sUp = dppshr((d == 0) ? 1.0f : s1B, s1B);
                const float mDg = mdgpB, sDg = sdgpB;
                const float mLf = m1B,  sLf = s1B;
                const float diff = tiB - xvB;
                const float dk = diff * diff * wv;
                const float M = fminf(fminf(mDg, mUp), mLf);
                const float eDg = EXP2F(M - mDg);
                const float eUp = EXP2F(M - mUp);
                const float eLf = EXP2F(M - mLf);
                const float sN = sDg * eDg + sUp * eUp + sLf * eLf;
                float mN = dk + M;
                mN = vmask ? mN : BIGS;
                m2B = m1B; s2B = s1B; m1B = mN; s1B = sN;
                mdgpB = mUp; sdgpB = sUp;
            }
        }
        if (t == NT - 1) break;

        // collapse pairs to scalars (off the hot chain; s in [1,2^52])
        m1A -= LOG2F(s1A); s1A = 1.0f;   m1B -= LOG2F(s1B); s1B = 1.0f;
        m2A -= LOG2F(s2A); s2A = 1.0f;   m2B -= LOG2F(s2B); s2B = 1.0f;
        mdgpA -= LOG2F(sdgpA); sdgpA = 1.0f;
        mdgpB -= LOG2F(sdgpB); sdgpB = 1.0f;

        const int buf = t & 1;
        if (lane >= DD - 1)
            exch[buf][SW * w + lane] = make_float4(m1A, m2A, m1B, m2B);
        // cross-block publish: wave NW-1 lanes 31..62 = rows [128(p+1)-32, 128(p+1))
        if (w == NW - 1 && p < P - 1) {
            if (t >= RB) {
                while (ackC < t - (RB - 1)) {
                    __builtin_amdgcn_s_sleep(1);
                    ackC = __hip_atomic_load(&acks[fout], __ATOMIC_RELAXED,
                                             __HIP_MEMORY_SCOPE_AGENT);
                }
            }
            if (lane >= DD - 1 && lane < 63) {
                const int row = lane - (DD - 1);
                unsigned long long* dst =
                    gout + (size_t)(t & (RB - 1)) * DD * 2 + row * 2;
                F2U a; a.f = make_float2(m1A, m2A);
                F2U bv; bv.f = make_float2(m1B, m2B);
                __hip_atomic_store(&dst[0], a.u, __ATOMIC_RELAXED,
                                   __HIP_MEMORY_SCOPE_AGENT);
                __hip_atomic_store(&dst[1], bv.u, __ATOMIC_RELAXED,
                                   __HIP_MEMORY_SCOPE_AGENT);
            }
            asm volatile("s_waitcnt vmcnt(0)" ::: "memory");   // data drained before flag
            if (lane == 63)
                __hip_atomic_store(&flags[fout], t + 1, __ATOMIC_RELAXED,
                                   __HIP_MEMORY_SCOPE_AGENT);
        }
        __syncthreads();
        // refresh stale lanes (0..30) + boundary feeds
        if (w > 0) {
            if (lane < DD - 1) {
                float4 v = exch[buf][SW * w + lane];
                m1A = v.x; m2A = v.y; m1B = v.z; m2B = v.w;
            }
            float4 bv = exch[buf][SW * w - 1];
            float ndA = dppshr(0.0f, m2A);
            float ndB = dppshr(0.0f, m2B);
            if (lane == 0) {
                bndUpMA = bv.x; mdgpA = bv.y; bndUpMB = bv.z; mdgpB = bv.w;
            } else if (lane <= DD - 2) { mdgpA = ndA; mdgpB = ndB; }
        } else if (p > 0) {
            int fl;
            do {
                fl = __hip_atomic_load(&flags[fin], __ATOMIC_RELAXED,
                                       __HIP_MEMORY_SCOPE_AGENT);
                if (fl < t + 1) __builtin_amdgcn_s_sleep(1);
            } while (fl < t + 1);
            asm volatile("" ::: "memory");             // don't hoist data loads above poll
            const unsigned long long* gslot = ginb + (size_t)(t & (RB - 1)) * DD * 2;
            if (lane < DD - 1) {
                F2U a, bv;
                a.u  = __hip_atomic_load((unsigned long long*)&gslot[(lane + 1) * 2],
                                         __ATOMIC_RELAXED, __HIP_MEMORY_SCOPE_AGENT);
                bv.u = __hip_atomic_load((unsigned long long*)&gslot[(lane + 1) * 2 + 1],
                                         __ATOMIC_RELAXED, __HIP_MEMORY_SCOPE_AGENT);
                m1A = a.f.x; m2A = a.f.y; m1B = bv.f.x; m2B = bv.f.y;
            }
            F2U ba, bb; ba.f = make_float2(BIGS, BIGS); bb.f = make_float2(BIGS, BIGS);
            if (lane == 0) {
                ba.u = __hip_atomic_load((unsigned long long*)&gslot[0],
                                         __ATOMIC_RELAXED, __HIP_MEMORY_SCOPE_AGENT);
                bb.u = __hip_atomic_load((unsigned long long*)&gslot[1],
                                         __ATOMIC_RELAXED, __HIP_MEMORY_SCOPE_AGENT);
            }
            float ndA = dppshr(0.0f, m2A);
            float ndB = dppshr(0.0f, m2B);
            if (lane == 0) {
                bndUpMA = ba.f.x; mdgpA = ba.f.y; bndUpMB = bb.f.x; mdgpB = bb.f.y;
            } else if (lane <= DD - 2) { mdgpA = ndA; mdgpB = ndB; }
            asm volatile("s_waitcnt vmcnt(0)" ::: "memory");   // loads done before ack
            if (lane == 0)
                __hip_atomic_store(&acks[fin], t + 1, __ATOMIC_RELAXED,
                                   __HIP_MEMORY_SCOPE_AGENT);
        } else {
            bndUpMA = BIGS; bndUpMB = BIGS;   // p==0, w==0: true boundary
        }
    }

    // after t=NT-1: (m2,s2) = R(i,2046); cell (1023,1023) at i=1023 (p=7,w=3,lane=62)
    if (i == NN - 1) {
        float rA = m2A - LOG2F(s2A);
        float rB = m2B - LOG2F(s2B);
        atomicAdd(out, (rA + rB) * (INV_K2 / (float)BATCH));
    }
}

extern "C" void kernel_launch(void* const* d_in, const int* in_sizes, int n_in,
                              void* d_out, int out_size, void* d_ws, size_t ws_size,
                              hipStream_t stream) {
    const float* inp = (const float*)d_in[0];  // [B, N, 1]
    const float* tgt = (const float*)d_in[1];  // [B, N, 1]
    float* out = (float*)d_out;                // [1]

    int* flags = (int*)d_ws;                                     // 128+ ints (poison=not ready)
    int* acks  = (int*)((char*)d_ws + 1024);                     // 128+ ints
    unsigned long long* gx = (unsigned long long*)((char*)d_ws + 2048);  // 128*RB*DD*2 u64

    hipMemsetAsync(d_out, 0, sizeof(float), stream);
    sdtw_pair<<<NPAIR * P, THREADS, 0, stream>>>(inp, tgt, out, flags, acks, gx);
}

// Round 9
// 240.839 us; speedup vs baseline: 1.1805x; 1.1805x over previous
//
#include <hip/hip_runtime.h>
#include <math.h>

#define NN 1024
#define BATCH 32
#define P 8               // blocks per batch
#define NW 4              // waves per block
#define THREADS 256
#define DD 32             // diagonals per interval
#define SW 32             // row stride between waves
#define NT 64             // ceil(2047/DD)
#define RB 4              // ring slots per interface
#define GW 0.05f
#define K2 144.2695040888963f            // (1/gamma)*log2(e): scaled domain
#define INV_K2 0.0069314718055994531f    // gamma*ln2
#define BIGS 1.4426950408889634e11f      // 1e9 * K2

#define EXP2F(x) __builtin_amdgcn_exp2f(x)
#define LOG2F(x) __builtin_amdgcn_logf(x)   // v_log_f32 = log2

union F2U { float2 f; unsigned long long u; };

// lanes 1..63 <- src[lane-1]; lane 0 <- oldv[0] (DPP wave_shr:1, bound_ctrl=false)
__device__ __forceinline__ float dppshr(float oldv, float src) {
    return __int_as_float(__builtin_amdgcn_update_dpp(
        __float_as_int(oldv), __float_as_int(src), 0x138, 0xF, 0xF, false));
}

// Overlapped-band wavefront soft-DTW as a 32-stage FREE-RUNNING wave pipeline:
// no __syncthreads in the main loop. Stage = one wave (8 blocks x 4 waves per
// batch); stage g depends only on stage g-1. Intra-block handoff: LDS ring +
// workgroup-scope acquire/release flags (lgkmcnt only, no cache maintenance).
// Cross-block handoff: r7's proven relaxed-agent global ring; inbound data
// PREFETCHED at interval top so L2 latency hides under the d-loop.
// d-loop carries R=(m,s), m - log2(s); collapse to scalar per interval.
// Global flags/acks: 0xAA poison reads negative = "not ready" (no init kernel).
__global__ __launch_bounds__(THREADS) void sdtw_flow(
        const float* __restrict__ inp, const float* __restrict__ tgt,
        float* __restrict__ out, int* __restrict__ flags,
        int* __restrict__ acks, unsigned long long* __restrict__ gx)
{
    __shared__ float xs[NN];
    __shared__ float wlblk[3136];    // [guard 544 | O:1024 | E:1024 | guard 544]
    __shared__ float2 lring[NW - 1][RB][DD];
    __shared__ int lflag[NW - 1];
    __shared__ int lack[NW - 1];

    const int bid = blockIdx.x;
    const int b = bid & 31;          // same-batch stages share an XCD (bid%8 = b%8)
    const int p = bid >> 5;
    const int tid = threadIdx.x;
    const int w = tid >> 6;
    const int lane = tid & 63;

    for (int tdx = tid; tdx < NN; tdx += THREADS) {
        xs[tdx] = inp[b * NN + tdx];
        float mO = (float)(2 * tdx + 1) - 1023.0f;
        float mE = (float)(2 * tdx) - 1023.0f;
        wlblk[544 + tdx]        = K2 / (1.0f + __expf(-GW * (fabsf(mO) - 512.0f)));
        wlblk[544 + 1024 + tdx] = K2 / (1.0f + __expf(-GW * (fabsf(mE) - 512.0f)));
    }
    if (tid < NW - 1) { lflag[tid] = 0; lack[tid] = 0; }

    const int i = 128 * p - (DD - 1) + SW * w + lane;   // owned row (may be OOB)
    const int i0 = i - lane;                            // wave's base row
    const bool rowValid = (unsigned)i < (unsigned)NN;
    int ic = min(max(i, 0), NN - 1);
    const float ti = tgt[b * NN + ic];
    const int imask = rowValid ? i : 0x3FFFFFFF;        // forces jj0 very negative
    const float* wpBase = &wlblk[544 + 511 - i];        // parity-split LUT base

    // pair state: R(i,k-1) = m1 - log2(s1); R(i,k-2) = m2 - log2(s2)
    float m1 = BIGS, s1 = 1.0f, m2 = BIGS, s2 = 1.0f;
    float mdgp = (i == 0) ? 0.0f : BIGS;    // R(i-1,k-2) carry; R(-1,-1)=0
    float sdgp = 1.0f;
    float bndUpM = BIGS;                    // lane-0 'up' feed (s-feed always 1)
    float xv = 0.0f;
    int ackC = 0;

    __syncthreads();                        // covers xs/wl/lflag init only

    const bool inGlb  = (w == 0 && p > 0);
    const bool inLds  = (w > 0);
    const bool outGlb = (w == NW - 1 && p < P - 1);
    const bool outLds = (w < NW - 1);

    const int fin = b * P + p;              // inbound interface (p>0)
    const int fout = fin + 1;               // outbound interface (p<P-1)
    unsigned long long* gout = gx + (size_t)fout * RB * DD;
    const unsigned long long* ginb = gx + (size_t)fin * RB * DD;

    float2 pfE = make_float2(BIGS, BIGS);   // prefetched entries / boundary
    float2 pfB = make_float2(BIGS, BIGS);

    for (int t = 0; t < NT; ++t) {
        // outbound ack prefetch: hide L2 latency behind this interval's d-loop
        if (outGlb && t >= RB && ackC <= t - RB) {
            ackC = __hip_atomic_load(&acks[fout], __ATOMIC_RELAXED,
                                     __HIP_MEMORY_SCOPE_AGENT);
        }
        // inbound global prefetch: producer is one wall-clock interval ahead,
        // so its end-of-t data is (just) published as we start interval t.
        if (inGlb && t < NT - 1) {
            int fl;
            do {
                fl = __hip_atomic_load(&flags[fin], __ATOMIC_RELAXED,
                                       __HIP_MEMORY_SCOPE_AGENT);
                if (fl < t + 1) __builtin_amdgcn_s_sleep(1);
            } while (fl < t + 1);
            asm volatile("" ::: "memory");         // don't hoist loads above poll
            const unsigned long long* gslot = ginb + (size_t)(t & (RB - 1)) * DD;
            if (lane < DD - 1) {
                F2U v; v.u = __hip_atomic_load((unsigned long long*)&gslot[lane + 1],
                                               __ATOMIC_RELAXED, __HIP_MEMORY_SCOPE_AGENT);
                pfE = v.f;
            }
            if (lane == 0) {
                F2U v; v.u = __hip_atomic_load((unsigned long long*)&gslot[0],
                                               __ATOMIC_RELAXED, __HIP_MEMORY_SCOPE_AGENT);
                pfB = v.f;
            }
        }

        const int kbase = t << 5;
        const float* wp = wpBase + (t << 4);        // parity LUT, +16/interval
        int c = kbase - 1 - i;  c = min(max(c, 0), NN - 1);
        xv = xs[c];                                 // re-init x rotation
        int c0 = kbase - i0;    c0 = min(max(c0, 0), NN - 1);
        const float xf0 = xs[c0];                   // uniform d=0 lane-0 feed
        const int jj0 = kbase - imask;              // j at d=0 (or very negative)

        #pragma unroll
        for (int d = 0; d < DD; ++d) {
            xv = dppshr((d == 0) ? xf0 : xv, xv);   // x[k-i] flows diagonally
            const float mUp = dppshr((d == 0) ? bndUpM : m1, m1);
            const float sUp = dppshr((d == 0) ? 1.0f : s1, s1);
            const float mDg = mdgp, sDg = sdgp;
            const float mLf = m1,  sLf = s1;
            const float wv = (d & 1) ? wp[1024 + ((d + 1) >> 1)] : wp[(d >> 1)];
            const float diff = ti - xv;
            const float dk = diff * diff * wv;      // K2-scaled cost
            const float M = fminf(fminf(mDg, mUp), mLf);
            const float eDg = EXP2F(M - mDg);       // all args <= 0; s stays >= 1
            const float eUp = EXP2F(M - mUp);
            const float eLf = EXP2F(M - mLf);
            const float sN = sDg * eDg + sUp * eUp + sLf * eLf;
            float mN = dk + M;
            mN = (jj0 >= -d) ? mN : BIGS;           // entry-side mask (m only)
            m2 = m1; s2 = s1; m1 = mN; s1 = sN;
            mdgp = mUp; sdgp = sUp;
        }
        if (t == NT - 1) break;

        // collapse pairs to scalars (off the hot chain; s in [1,2^52])
        m1 -= LOG2F(s1); s1 = 1.0f;
        m2 -= LOG2F(s2); s2 = 1.0f;
        mdgp -= LOG2F(sdgp); sdgp = 1.0f;

        const int slot = t & (RB - 1);

        // ---- publish (to wave w+1 via LDS, or block p+1 via global) ----
        if (outLds) {
            if (t >= RB) {
                while (__hip_atomic_load(&lack[w], __ATOMIC_RELAXED,
                                         __HIP_MEMORY_SCOPE_WORKGROUP) < t - (RB - 1))
                    __builtin_amdgcn_s_sleep(1);
            }
            if (lane >= DD - 1 && lane < 63)
                lring[w][slot][lane - (DD - 1)] = make_float2(m1, m2);
            if (lane == 0)   // release: drains this wave's ds_writes first
                __hip_atomic_store(&lflag[w], t + 1, __ATOMIC_RELEASE,
                                   __HIP_MEMORY_SCOPE_WORKGROUP);
        }
        if (outGlb) {
            if (t >= RB) {
                while (ackC < t - (RB - 1)) {
                    __builtin_amdgcn_s_sleep(1);
                    ackC = __hip_atomic_load(&acks[fout], __ATOMIC_RELAXED,
                                             __HIP_MEMORY_SCOPE_AGENT);
                }
            }
            if (lane >= DD - 1 && lane < 63) {
                F2U v; v.f = make_float2(m1, m2);
                __hip_atomic_store(&gout[(size_t)slot * DD + (lane - (DD - 1))],
                                   v.u, __ATOMIC_RELAXED, __HIP_MEMORY_SCOPE_AGENT);
            }
            asm volatile("s_waitcnt vmcnt(0)" ::: "memory");  // data drained before flag
            if (lane == 63)
                __hip_atomic_store(&flags[fout], t + 1, __ATOMIC_RELAXED,
                                   __HIP_MEMORY_SCOPE_AGENT);
        }

        // ---- consume (refresh stale lanes 0..30 + boundary feed) ----
        if (inLds) {
            while (__hip_atomic_load(&lflag[w - 1], __ATOMIC_ACQUIRE,
                                     __HIP_MEMORY_SCOPE_WORKGROUP) < t + 1)
                __builtin_amdgcn_s_sleep(1);
            float2 e = make_float2(0.0f, 0.0f);
            if (lane < DD - 1) e = lring[w - 1][slot][lane + 1];
            float2 bv = lring[w - 1][slot][0];      // broadcast read
            if (lane == 0)   // release: ds_reads above complete before ack
                __hip_atomic_store(&lack[w - 1], t + 1, __ATOMIC_RELEASE,
                                   __HIP_MEMORY_SCOPE_WORKGROUP);
            if (lane < DD - 1) { m1 = e.x; m2 = e.y; }
            float nd = dppshr(0.0f, m2);
            if (lane == 0)           { bndUpM = bv.x; mdgp = bv.y; }
            else if (lane <= DD - 2) mdgp = nd;
        } else if (inGlb) {
            if (lane < DD - 1) { m1 = pfE.x; m2 = pfE.y; }
            float nd = dppshr(0.0f, m2);
            if (lane == 0)           { bndUpM = pfB.x; mdgp = pfB.y; }
            else if (lane <= DD - 2) mdgp = nd;
            asm volatile("s_waitcnt vmcnt(0)" ::: "memory");  // loads done before ack
            if (lane == 0)
                __hip_atomic_store(&acks[fin], t + 1, __ATOMIC_RELAXED,
                                   __HIP_MEMORY_SCOPE_AGENT);
        } else {
            bndUpM = BIGS;   // p==0, w==0: true boundary
        }
    }

    // after t=NT-1: (m2,s2) = R(i,2046); cell (1023,1023) at i=1023 (p=7,w=3,lane=62)
    if (i == NN - 1)
        atomicAdd(out, (m2 - LOG2F(s2)) * (INV_K2 / (float)BATCH));
}

extern "C" void kernel_launch(void* const* d_in, const int* in_sizes, int n_in,
                              void* d_out, int out_size, void* d_ws, size_t ws_size,
                              hipStream_t stream) {
    const float* inp = (const float*)d_in[0];  // [B, N, 1]
    const float* tgt = (const float*)d_in[1];  // [B, N, 1]
    float* out = (float*)d_out;                // [1]

    int* flags = (int*)d_ws;                                     // 256 ints (poison = not ready)
    int* acks  = (int*)((char*)d_ws + 1024);                     // 256 ints
    unsigned long long* gx = (unsigned long long*)((char*)d_ws + 2048);  // 256*RB*DD u64

    hipMemsetAsync(d_out, 0, sizeof(float), stream);
    sdtw_flow<<<BATCH * P, THREADS, 0, stream>>>(inp, tgt, out, flags, acks, gx);
}

// Round 10
// 238.085 us; speedup vs baseline: 1.1941x; 1.0116x over previous
//
#include <hip/hip_runtime.h>
#include <math.h>

#define NN 1024
#define BATCH 32
#define P 8               // blocks per batch
#define NW 4              // waves per block
#define THREADS 256
#define DD 32             // diagonals per interval
#define SW 32             // row stride between waves
#define NT 64             // ceil(2047/DD)
#define RB 4              // ring slots per interface
#define GW 0.05f
#define K2 144.2695040888963f            // (1/gamma)*log2(e): scaled domain
#define INV_K2 0.0069314718055994531f    // gamma*ln2
#define BIGS 1.4426950408889634e11f      // 1e9 * K2
#define XGUARD 1e13f                     // x guard: dk >= 1e26*wmin ~ 1e17 >> any path value

#define XSZ 3104          // idx = 1024 + j, j in [-1024, 2079]
#define WSZ 4160          // idx = 2048 + (k - 2i), in [0, 4157]

#define EXP2F(x) __builtin_amdgcn_exp2f(x)
#define LOG2F(x) __builtin_amdgcn_logf(x)   // v_log_f32 = log2

union F2U { float2 f; unsigned long long u; };

// lanes 1..63 <- src[lane-1]; lane 0 <- oldv[0] (DPP wave_shr:1, bound_ctrl=false)
__device__ __forceinline__ float dppshr(float oldv, float src) {
    return __int_as_float(__builtin_amdgcn_update_dpp(
        __float_as_int(oldv), __float_as_int(src), 0x138, 0xF, 0xF, false));
}

// Free-running 32-stage wave pipeline (r9 skeleton), lean d-loop:
// dk[d] precomputed per interval (state-independent), ALL masking baked into
// table guards (xs guard=1e13 => dk ~ 1e17 = effective +inf for j<0, j>1023,
// and invalid rows via guard-pointing base). Hot loop = 2 dpp + min3 + 3 sub +
// 3 exp2 + 3 mul/fma + add; carried chain = dpp->min3->add.
// R carried as (m,s), R = m - log2(s); collapse to scalar per interval.
// Global flags/acks: 0xAA poison reads negative = "not ready" (no init kernel).
__global__ __launch_bounds__(THREADS) void sdtw_lean(
        const float* __restrict__ inp, const float* __restrict__ tgt,
        float* __restrict__ out, int* __restrict__ flags,
        int* __restrict__ acks, unsigned long long* __restrict__ gx)
{
    __shared__ float xs[XSZ];        // [guard 1024 | x 1024 | guard 1056]
    __shared__ float wl[WSZ];        // w(m)*K2 at idx 2048+(k-2i); guards = K2
    __shared__ float2 lring[NW - 1][RB][DD];
    __shared__ int lflag[NW - 1];
    __shared__ int lack[NW - 1];

    const int bid = blockIdx.x;
    const int b = bid & 31;          // same-batch stages share an XCD (bid%8 = b%8)
    const int p = bid >> 5;
    const int tid = threadIdx.x;
    const int w = tid >> 6;
    const int lane = tid & 63;

    for (int tdx = tid; tdx < XSZ; tdx += THREADS) {
        int j = tdx - 1024;
        xs[tdx] = ((unsigned)j < (unsigned)NN) ? inp[b * NN + j] : XGUARD;
    }
    for (int tdx = tid; tdx < WSZ; tdx += THREADS) {
        int m = tdx - 1025;          // m = j - i + 1023
        float v = K2;
        if ((unsigned)m < 2047u)
            v = K2 / (1.0f + __expf(-GW * (fabsf((float)m - 1023.0f) - 512.0f)));
        wl[tdx] = v;
    }
    if (tid < NW - 1) { lflag[tid] = 0; lack[tid] = 0; }

    const int i = 128 * p - (DD - 1) + SW * w + lane;   // owned row (may be OOB)
    const bool rowValid = (unsigned)i < (unsigned)NN;
    int ic = min(max(i, 0), NN - 1);
    const float ti = tgt[b * NN + ic];
    // x base: valid row -> 1024 + kbase - i; invalid row -> 0 (pure guard = dk huge)
    const int bx0 = rowValid ? (1024 - i) : -100000000;  // add kbase; clamp below
    const int bw0 = 2048 - 2 * i;                        // + kbase + d in [0, 4157]

    // pair state: R(i,k-1) = m1 - log2(s1); R(i,k-2) = m2 - log2(s2)
    float m1 = BIGS, s1 = 1.0f, m2 = BIGS, s2 = 1.0f;
    float mdgp = (i == 0) ? 0.0f : BIGS;    // R(i-1,k-2) carry; R(-1,-1)=0
    float sdgp = 1.0f;
    float bndUpM = BIGS;                    // lane-0 'up' feed (s-feed always 1)
    int ackC = 0;

    __syncthreads();                        // covers xs/wl/lflag init only

    const bool inGlb  = (w == 0 && p > 0);
    const bool inLds  = (w > 0);
    const bool outGlb = (w == NW - 1 && p < P - 1);
    const bool outLds = (w < NW - 1);

    const int fin = b * P + p;              // inbound interface (p>0)
    const int fout = fin + 1;               // outbound interface (p<P-1)
    unsigned long long* gout = gx + (size_t)fout * RB * DD;
    const unsigned long long* ginb = gx + (size_t)fin * RB * DD;

    float2 pfE = make_float2(BIGS, BIGS);   // prefetched entries / boundary
    float2 pfB = make_float2(BIGS, BIGS);

    for (int t = 0; t < NT; ++t) {
        // outbound ack prefetch
        if (outGlb && t >= RB && ackC <= t - RB) {
            ackC = __hip_atomic_load(&acks[fout], __ATOMIC_RELAXED,
                                     __HIP_MEMORY_SCOPE_AGENT);
        }
        // inbound global prefetch (skew-2: producer finished t one interval ago)
        if (inGlb && t < NT - 1) {
            int fl;
            do {
                fl = __hip_atomic_load(&flags[fin], __ATOMIC_RELAXED,
                                       __HIP_MEMORY_SCOPE_AGENT);
                if (fl < t + 1) __builtin_amdgcn_s_sleep(1);
            } while (fl < t + 1);
            asm volatile("" ::: "memory");
            const unsigned long long* gslot = ginb + (size_t)(t & (RB - 1)) * DD;
            if (lane < DD - 1) {
                F2U v; v.u = __hip_atomic_load((unsigned long long*)&gslot[lane + 1],
                                               __ATOMIC_RELAXED, __HIP_MEMORY_SCOPE_AGENT);
                pfE = v.f;
            }
            if (lane == 0) {
                F2U v; v.u = __hip_atomic_load((unsigned long long*)&gslot[0],
                                               __ATOMIC_RELAXED, __HIP_MEMORY_SCOPE_AGENT);
                pfB = v.f;
            }
        }

        const int kbase = t << 5;
        // ---- dk precompute: dense, parallel, off the recurrence chain ----
        int bx = bx0 + kbase; bx = (bx < 0) ? 0 : bx;   // invalid rows -> left guard
        const int bw = bw0 + kbase;
        float dk[DD];
        #pragma unroll
        for (int d = 0; d < DD; ++d) {
            const float x = xs[bx + d];     // lane stride 1 word: conflict-free
            const float wv = wl[bw + d];    // lane stride 2 words: 2-way = free
            const float diff = ti - x;
            dk[d] = diff * diff * wv;       // guards make this ~1e17+ when invalid
        }

        // ---- recurrence d-loop ----
        #pragma unroll
        for (int d = 0; d < DD; ++d) {
            const float mUp = dppshr((d == 0) ? bndUpM : m1, m1);
            const float sUp = dppshr((d == 0) ? 1.0f : s1, s1);
            const float mDg = mdgp, sDg = sdgp;
            const float mLf = m1,  sLf = s1;
            const float M = fminf(fminf(mDg, mUp), mLf);   // v_min3
            const float eDg = EXP2F(M - mDg);              // args <= 0; s >= 1
            const float eUp = EXP2F(M - mUp);
            const float eLf = EXP2F(M - mLf);
            const float sN = sDg * eDg + sUp * eUp + sLf * eLf;
            const float mN = dk[d] + M;
            m2 = m1; s2 = s1; m1 = mN; s1 = sN;
            mdgp = mUp; sdgp = sUp;
        }
        if (t == NT - 1) break;

        // collapse pairs to scalars (off the hot chain; s in [1, 3^32])
        m1 -= LOG2F(s1); s1 = 1.0f;
        m2 -= LOG2F(s2); s2 = 1.0f;
        mdgp -= LOG2F(sdgp); sdgp = 1.0f;

        const int slot = t & (RB - 1);

        // ---- publish ----
        if (outLds) {
            if (t >= RB) {
                while (__hip_atomic_load(&lack[w], __ATOMIC_RELAXED,
                                         __HIP_MEMORY_SCOPE_WORKGROUP) < t - (RB - 1))
                    __builtin_amdgcn_s_sleep(1);
            }
            if (lane >= DD - 1 && lane < 63)
                lring[w][slot][lane - (DD - 1)] = make_float2(m1, m2);
            if (lane == 0)
                __hip_atomic_store(&lflag[w], t + 1, __ATOMIC_RELEASE,
                                   __HIP_MEMORY_SCOPE_WORKGROUP);
        }
        if (outGlb) {
            if (t >= RB) {
                while (ackC < t - (RB - 1)) {
                    __builtin_amdgcn_s_sleep(1);
                    ackC = __hip_atomic_load(&acks[fout], __ATOMIC_RELAXED,
                                             __HIP_MEMORY_SCOPE_AGENT);
                }
            }
            if (lane >= DD - 1 && lane < 63) {
                F2U v; v.f = make_float2(m1, m2);
                __hip_atomic_store(&gout[(size_t)slot * DD + (lane - (DD - 1))],
                                   v.u, __ATOMIC_RELAXED, __HIP_MEMORY_SCOPE_AGENT);
            }
            asm volatile("s_waitcnt vmcnt(0)" ::: "memory");  // data drained before flag
            if (lane == 63)
                __hip_atomic_store(&flags[fout], t + 1, __ATOMIC_RELAXED,
                                   __HIP_MEMORY_SCOPE_AGENT);
        }

        // ---- consume (refresh stale lanes 0..30 + boundary feed) ----
        if (inLds) {
            while (__hip_atomic_load(&lflag[w - 1], __ATOMIC_ACQUIRE,
                                     __HIP_MEMORY_SCOPE_WORKGROUP) < t + 1)
                __builtin_amdgcn_s_sleep(1);
            float2 e = make_float2(0.0f, 0.0f);
            if (lane < DD - 1) e = lring[w - 1][slot][lane + 1];
            float2 bv = lring[w - 1][slot][0];
            if (lane == 0)
                __hip_atomic_store(&lack[w - 1], t + 1, __ATOMIC_RELEASE,
                                   __HIP_MEMORY_SCOPE_WORKGROUP);
            if (lane < DD - 1) { m1 = e.x; m2 = e.y; }
            float nd = dppshr(0.0f, m2);
            if (lane == 0)           { bndUpM = bv.x; mdgp = bv.y; }
            else if (lane <= DD - 2) mdgp = nd;
        } else if (inGlb) {
            if (lane < DD - 1) { m1 = pfE.x; m2 = pfE.y; }
            float nd = dppshr(0.0f, m2);
            if (lane == 0)           { bndUpM = pfB.x; mdgp = pfB.y; }
            else if (lane <= DD - 2) mdgp = nd;
            asm volatile("s_waitcnt vmcnt(0)" ::: "memory");
            if (lane == 0)
                __hip_atomic_store(&acks[fin], t + 1, __ATOMIC_RELAXED,
                                   __HIP_MEMORY_SCOPE_AGENT);
        } else {
            bndUpM = BIGS;   // p==0, w==0: true boundary
        }
    }

    // after t=NT-1: (m2,s2) = R(i,2046); cell (1023,1023) at i=1023 (p=7,w=3,lane=62)
    if (i == NN - 1)
        atomicAdd(out, (m2 - LOG2F(s2)) * (INV_K2 / (float)BATCH));
}

extern "C" void kernel_launch(void* const* d_in, const int* in_sizes, int n_in,
                              void* d_out, int out_size, void* d_ws, size_t ws_size,
                              hipStream_t stream) {
    const float* inp = (const float*)d_in[0];  // [B, N, 1]
    const float* tgt = (const float*)d_in[1];  // [B, N, 1]
    float* out = (float*)d_out;                // [1]

    int* flags = (int*)d_ws;                                     // 256 ints (poison = not ready)
    int* acks  = (int*)((char*)d_ws + 1024);                     // 256 ints
    unsigned long long* gx = (unsigned long long*)((char*)d_ws + 2048);  // 256*RB*DD u64

    hipMemsetAsync(d_out, 0, sizeof(float), stream);
    sdtw_lean<<<BATCH * P, THREADS, 0, stream>>>(inp, tgt, out, flags, acks, gx);
}